// Round 1
// baseline (1643.801 us; speedup 1.0000x reference)
//
#include <hip/hip_runtime.h>
#include <hip/hip_bf16.h>

// Problem constants (from reference)
#define BSZ      2
#define LTOK     21760            // 128*128 + 64*64 + 32*32 + 16*16
#define NTOK     (BSZ * LTOK)     // 43520
#define DMODEL   256
#define DFFN     1024
#define NHEADS   8
#define NPOINTS  4
#define NLEVELS  4
#define DHEAD    32

// ---------------------------------------------------------------------------
// Generic tiled fp32 GEMM:  C[M x Nc] = (A [+ A2]) @ W[K x Nc] + bias
// BM=64, BN=64, BK=16, 256 threads, 4x4 micro-tile per thread.
// Optional relu epilogue, optional per-row zero mask (padding_mask).
// M % 64 == 0, Nc % 64 == 0, K % 16 == 0 guaranteed by problem shapes.
// ---------------------------------------------------------------------------
#define BM 64
#define BN 64
#define BK 16

__global__ __launch_bounds__(256) void gemm_f32(
    const float* __restrict__ A, const float* __restrict__ A2,
    const float* __restrict__ W, const float* __restrict__ bias,
    float* __restrict__ C, int M, int K, int Nc, int relu,
    const unsigned char* __restrict__ mask)
{
    __shared__ float As[BK][BM + 4];  // transposed A tile, +4 pad keeps 16B align
    __shared__ float Ws[BK][BN];

    const int tid = threadIdx.x;
    const int bm = blockIdx.y * BM;
    const int bn = blockIdx.x * BN;
    const int tx = tid & 15;          // col group (4 cols each)
    const int ty = tid >> 4;          // row group (4 rows each)

    // global-load assignments
    const int arow = tid >> 2;        // 0..63  (row within A tile)
    const int akg  = (tid & 3) * 4;   // k offset 0,4,8,12
    const int wk   = tid >> 4;        // 0..15  (k within W tile)
    const int wcg  = (tid & 15) * 4;  // col offset within W tile

    float acc[4][4] = {{0.f}};

    for (int k0 = 0; k0 < K; k0 += BK) {
        // stage A tile (transposed)
        {
            const size_t aoff = (size_t)(bm + arow) * K + k0 + akg;
            float4 av = *(const float4*)(A + aoff);
            if (A2) {
                const float4 pv = *(const float4*)(A2 + aoff);
                av.x += pv.x; av.y += pv.y; av.z += pv.z; av.w += pv.w;
            }
            As[akg + 0][arow] = av.x;
            As[akg + 1][arow] = av.y;
            As[akg + 2][arow] = av.z;
            As[akg + 3][arow] = av.w;
        }
        // stage W tile
        {
            const float4 wv = *(const float4*)(W + (size_t)(k0 + wk) * Nc + bn + wcg);
            *(float4*)&Ws[wk][wcg] = wv;
        }
        __syncthreads();

        #pragma unroll
        for (int k = 0; k < BK; ++k) {
            const float4 a  = *(const float4*)&As[k][ty * 4];
            const float4 bv = *(const float4*)&Ws[k][tx * 4];
            const float av[4] = {a.x, a.y, a.z, a.w};
            const float bw[4] = {bv.x, bv.y, bv.z, bv.w};
            #pragma unroll
            for (int ii = 0; ii < 4; ++ii)
                #pragma unroll
                for (int jj = 0; jj < 4; ++jj)
                    acc[ii][jj] = fmaf(av[ii], bw[jj], acc[ii][jj]);
        }
        __syncthreads();
    }

    // epilogue
    float4 bb = make_float4(0.f, 0.f, 0.f, 0.f);
    if (bias) bb = *(const float4*)(bias + bn + tx * 4);

    #pragma unroll
    for (int ii = 0; ii < 4; ++ii) {
        const int row = bm + ty * 4 + ii;
        float4 o;
        o.x = acc[ii][0] + bb.x;
        o.y = acc[ii][1] + bb.y;
        o.z = acc[ii][2] + bb.z;
        o.w = acc[ii][3] + bb.w;
        if (relu) {
            o.x = fmaxf(o.x, 0.f); o.y = fmaxf(o.y, 0.f);
            o.z = fmaxf(o.z, 0.f); o.w = fmaxf(o.w, 0.f);
        }
        if (mask && mask[row]) { o.x = 0.f; o.y = 0.f; o.z = 0.f; o.w = 0.f; }
        *(float4*)(C + (size_t)row * Nc + bn + tx * 4) = o;
    }
}

// ---------------------------------------------------------------------------
// Fused per-head softmax + bilinear deformable sampling.
// One block (256 threads) per token. Phase A: threads 0..127 = (head, point)
// compute sampling corner indices/weights + softmax over the 16 points of
// each head (16-lane shuffle groups). Phase B: threads = (head, dim) gather.
// ---------------------------------------------------------------------------
__global__ __launch_bounds__(256) void sample_kernel(
    const float* __restrict__ value, const float* __restrict__ offb,
    const float* __restrict__ attnb, const float* __restrict__ ref,
    const int* __restrict__ sshapes, const int* __restrict__ lstart,
    float* __restrict__ samp)
{
    __shared__ float s_w[128][4];
    __shared__ int   s_i[128][4];
    __shared__ float s_a[128];

    const int i = blockIdx.x;          // token index in [0, NTOK)
    const int b = i / LTOK;
    const int t = threadIdx.x;

    if (t < 128) {
        const int h  = t >> 4;
        const int p  = t & 15;
        const int l  = p >> 2;
        const int pp = p & 3;
        const int H = sshapes[2 * l], W = sshapes[2 * l + 1];
        const float Wf = (float)W, Hf = (float)H;

        const float ox = offb[(size_t)i * 256 + h * 32 + l * 8 + pp * 2 + 0];
        const float oy = offb[(size_t)i * 256 + h * 32 + l * 8 + pp * 2 + 1];
        const float rx = ref[(size_t)i * 8 + l * 2 + 0];
        const float ry = ref[(size_t)i * 8 + l * 2 + 1];

        const float lx = rx + ox / Wf;
        const float ly = ry + oy / Hf;
        const float x = lx * Wf - 0.5f;
        const float y = ly * Hf - 0.5f;
        const float x0 = floorf(x), y0 = floorf(y);
        const float dx = x - x0, dy = y - y0;
        const int x0i = (int)x0, y0i = (int)y0;
        const int s = lstart[l];

        const float cw[4] = {(1.f - dx) * (1.f - dy), dx * (1.f - dy),
                             (1.f - dx) * dy,         dx * dy};
        const int cx[4] = {x0i, x0i + 1, x0i,     x0i + 1};
        const int cy[4] = {y0i, y0i,     y0i + 1, y0i + 1};
        #pragma unroll
        for (int c = 0; c < 4; ++c) {
            const bool valid = (cx[c] >= 0) & (cx[c] < W) & (cy[c] >= 0) & (cy[c] < H);
            const int xi = min(max(cx[c], 0), W - 1);
            const int yi = min(max(cy[c], 0), H - 1);
            s_i[t][c] = s + yi * W + xi;
            s_w[t][c] = valid ? cw[c] : 0.f;
        }

        // softmax over the 16 points of this head (lanes t..t|15 form a group)
        const float a = attnb[(size_t)i * 128 + t];
        float mx = a;
        #pragma unroll
        for (int m = 8; m; m >>= 1) mx = fmaxf(mx, __shfl_xor(mx, m, 16));
        const float e = __expf(a - mx);
        float ssum = e;
        #pragma unroll
        for (int m = 8; m; m >>= 1) ssum += __shfl_xor(ssum, m, 16);
        s_a[t] = e / ssum;
    }
    __syncthreads();

    const int h = t >> 5;
    const int d = t & 31;
    const size_t vbase = ((size_t)b * LTOK) * 256 + h * 32 + d;
    float acc = 0.f;
    #pragma unroll
    for (int p = 0; p < 16; ++p) {
        const int sl = h * 16 + p;
        const float aw = s_a[sl];
        #pragma unroll
        for (int c = 0; c < 4; ++c) {
            const float w = s_w[sl][c] * aw;
            const int idx = s_i[sl][c];
            acc = fmaf(w, value[vbase + (size_t)idx * 256], acc);
        }
    }
    samp[(size_t)i * 256 + t] = acc;
}

// ---------------------------------------------------------------------------
// LayerNorm over D=256: out = LN(a + b) * g + be. One wave (64 lanes) per
// token, float4 per lane, full-wave shuffle butterfly reduction.
// ---------------------------------------------------------------------------
__global__ __launch_bounds__(256) void ln_kernel(
    const float* __restrict__ a, const float* __restrict__ b,
    const float* __restrict__ g, const float* __restrict__ be,
    float* __restrict__ out)
{
    const int wid  = threadIdx.x >> 6;
    const int lane = threadIdx.x & 63;
    const int tok  = blockIdx.x * 4 + wid;
    const size_t base = (size_t)tok * 256 + lane * 4;

    const float4 va = *(const float4*)(a + base);
    const float4 vb = *(const float4*)(b + base);
    float4 v;
    v.x = va.x + vb.x; v.y = va.y + vb.y; v.z = va.z + vb.z; v.w = va.w + vb.w;

    float s  = v.x + v.y + v.z + v.w;
    float sq = v.x * v.x + v.y * v.y + v.z * v.z + v.w * v.w;
    #pragma unroll
    for (int m = 32; m; m >>= 1) {
        s  += __shfl_xor(s, m, 64);
        sq += __shfl_xor(sq, m, 64);
    }
    const float mean = s * (1.f / 256.f);
    const float var  = sq * (1.f / 256.f) - mean * mean;
    const float rs   = rsqrtf(var + 1e-5f);

    const float4 g4 = *(const float4*)(g + lane * 4);
    const float4 b4 = *(const float4*)(be + lane * 4);
    float4 o;
    o.x = (v.x - mean) * rs * g4.x + b4.x;
    o.y = (v.y - mean) * rs * g4.y + b4.y;
    o.z = (v.z - mean) * rs * g4.z + b4.z;
    o.w = (v.w - mean) * rs * g4.w + b4.w;
    *(float4*)(out + base) = o;
}

// ---------------------------------------------------------------------------
extern "C" void kernel_launch(void* const* d_in, const int* in_sizes, int n_in,
                              void* d_out, int out_size, void* d_ws, size_t ws_size,
                              hipStream_t stream)
{
    const float* src   = (const float*)d_in[0];
    const float* pos   = (const float*)d_in[1];
    const float* ref   = (const float*)d_in[2];
    const int*   sshap = (const int*)d_in[3];
    const int*   lstrt = (const int*)d_in[4];
    const unsigned char* mask = (const unsigned char*)d_in[5];
    const float* w_off = (const float*)d_in[6];
    const float* b_off = (const float*)d_in[7];
    const float* w_att = (const float*)d_in[8];
    const float* b_att = (const float*)d_in[9];
    const float* w_val = (const float*)d_in[10];
    const float* b_val = (const float*)d_in[11];
    const float* w_out = (const float*)d_in[12];
    const float* b_out = (const float*)d_in[13];
    const float* ln1g  = (const float*)d_in[14];
    const float* ln1b  = (const float*)d_in[15];
    const float* w1    = (const float*)d_in[16];
    const float* b1    = (const float*)d_in[17];
    const float* w2    = (const float*)d_in[18];
    const float* b2    = (const float*)d_in[19];
    const float* ln2g  = (const float*)d_in[20];
    const float* ln2b  = (const float*)d_in[21];
    float* out = (float*)d_out;

    const size_t SZ = (size_t)NTOK * 256;   // 11,141,120 floats
    float* ws    = (float*)d_ws;
    float* valb  = ws;                      // value  (later: y = attn_out, then ffn_out)
    float* offbf = ws + SZ;                 // off    (later: x after LN1)
    float* attbf = ws + 2 * SZ;             // attn logits (N*128)
    float* sampb = ws + 2 * SZ + SZ / 2;    // sampled (later: ffn hidden chunk)

    const dim3 blk(256);

    // value = src @ w_val + b_val  (masked)
    gemm_f32<<<dim3(256 / BN, NTOK / BM), blk, 0, stream>>>(
        src, nullptr, w_val, b_val, valb, NTOK, 256, 256, 0, mask);
    // off = (src+pos) @ w_off + b_off
    gemm_f32<<<dim3(256 / BN, NTOK / BM), blk, 0, stream>>>(
        src, pos, w_off, b_off, offbf, NTOK, 256, 256, 0, nullptr);
    // attn logits = (src+pos) @ w_attn + b_attn
    gemm_f32<<<dim3(128 / BN, NTOK / BM), blk, 0, stream>>>(
        src, pos, w_att, b_att, attbf, NTOK, 256, 128, 0, nullptr);

    // softmax + bilinear sampling -> sampb
    sample_kernel<<<dim3(NTOK), blk, 0, stream>>>(
        valb, offbf, attbf, ref, sshap, lstrt, sampb);

    // attn_out = samp @ w_out + b_out  -> valb (value dead)
    gemm_f32<<<dim3(256 / BN, NTOK / BM), blk, 0, stream>>>(
        sampb, nullptr, w_out, b_out, valb, NTOK, 256, 256, 0, nullptr);

    // x = LN1(src + attn_out) -> offbf (off dead)
    ln_kernel<<<dim3(NTOK / 4), blk, 0, stream>>>(src, valb, ln1g, ln1b, offbf);

    // FFN in 4 token chunks; hidden chunk reuses sampb (exactly SZ floats)
    const int CH = NTOK / 4;  // 10880 tokens
    for (int c = 0; c < 4; ++c) {
        const float* xc = offbf + (size_t)c * CH * 256;
        float* hc = sampb;
        float* fc = valb + (size_t)c * CH * 256;
        gemm_f32<<<dim3(DFFN / BN, CH / BM), blk, 0, stream>>>(
            xc, nullptr, w1, b1, hc, CH, 256, DFFN, 1, nullptr);
        gemm_f32<<<dim3(256 / BN, CH / BM), blk, 0, stream>>>(
            hc, nullptr, w2, b2, fc, CH, DFFN, 256, 0, nullptr);
    }

    // out = LN2(x + ffn)
    ln_kernel<<<dim3(NTOK / 4), blk, 0, stream>>>(offbf, valb, ln2g, ln2b, out);
}

// Round 2
// 715.893 us; speedup vs baseline: 2.2962x; 2.2962x over previous
//
#include <hip/hip_runtime.h>
#include <hip/hip_bf16.h>

// Problem constants
#define BSZ      2
#define LTOK     21760            // 128*128 + 64*64 + 32*32 + 16*16
#define NTOK     (BSZ * LTOK)     // 43520 = 128 * 340
#define DMODEL   256
#define DFFN     1024

typedef __attribute__((ext_vector_type(8))) short short8;   // 8 bf16 = 4 VGPRs
typedef __attribute__((ext_vector_type(4))) float f32x4;

__device__ __forceinline__ unsigned short f2bf(float x) {
    __hip_bfloat16 h = __float2bfloat16(x);
    return *reinterpret_cast<unsigned short*>(&h);
}
__device__ __forceinline__ float bf2f(unsigned short u) {
    union { unsigned int i; float f; } c; c.i = ((unsigned int)u) << 16; return c.f;
}

// ---------------------------------------------------------------------------
// bf16 MFMA GEMM:  C[M x N] = A @ Bt^T (+bias) with Bt = [N][K] bf16.
// 128x128 tile, BK=32, 256 threads = 4 waves in 2x2, each wave 4x4 MFMA
// tiles of 16x16x32. LDS tiles in MFMA *fragment order*: sub-tile s
// (16 rows x 32 k) occupies 64 slots of 16 B indexed by lane
// (m = lane&15, k = (lane>>4)*8 .. +8)  -> ds_read_b128 at lane*16,
// conflict-free, and staging is one 16 B store per slot.
// amode 0: A fp32 [M][K] (+optional A2 add), cast to bf16 in staging.
// amode 1: A bf16 [M][K].
// Epilogue: +bias, optional relu, optional per-row zero mask;
// writes fp32 Cf and/or bf16 Cb.
// ---------------------------------------------------------------------------
#define TM 128
#define TN 128
#define TBK 32

__global__ __launch_bounds__(256) void gemm_mfma(
    const void* __restrict__ Av, const float* __restrict__ A2,
    const unsigned short* __restrict__ Bt, const float* __restrict__ bias,
    float* __restrict__ Cf, unsigned short* __restrict__ Cb,
    int M, int N, int K, int amode, int relu,
    const unsigned char* __restrict__ mask)
{
    __shared__ __align__(16) unsigned short sA[TM * TBK];   // 8 KB
    __shared__ __align__(16) unsigned short sB[TN * TBK];   // 8 KB

    const int tid  = threadIdx.x;
    const int lane = tid & 63;
    const int wave = tid >> 6;
    const int wm = wave >> 1, wn = wave & 1;

    const int bm = blockIdx.y * TM;
    const int bn = blockIdx.x * TN;

    const int sr = tid >> 6;           // staging sub-tile base (0..3)
    const int fr = lane & 15;          // row within sub-tile
    const int fk = (lane >> 4) * 8;    // k offset (0,8,16,24)

    f32x4 acc[4][4];
    #pragma unroll
    for (int i = 0; i < 4; ++i)
        #pragma unroll
        for (int j = 0; j < 4; ++j)
            acc[i][j] = (f32x4){0.f, 0.f, 0.f, 0.f};

    for (int k0 = 0; k0 < K; k0 += TBK) {
        // ---- stage A (sub-tiles sr, sr+4) ----
        #pragma unroll
        for (int rr = 0; rr < 2; ++rr) {
            const int s = sr + rr * 4;
            const size_t grow = (size_t)(bm + s * 16 + fr);
            unsigned short* dst = &sA[s * 512 + lane * 8];
            if (amode == 0) {
                const float* Af = (const float*)Av + grow * K + k0 + fk;
                float4 v0 = *(const float4*)Af;
                float4 v1 = *(const float4*)(Af + 4);
                if (A2) {
                    const float* Pf = A2 + grow * K + k0 + fk;
                    const float4 p0 = *(const float4*)Pf;
                    const float4 p1 = *(const float4*)(Pf + 4);
                    v0.x += p0.x; v0.y += p0.y; v0.z += p0.z; v0.w += p0.w;
                    v1.x += p1.x; v1.y += p1.y; v1.z += p1.z; v1.w += p1.w;
                }
                const unsigned int p0 = (unsigned)f2bf(v0.x) | ((unsigned)f2bf(v0.y) << 16);
                const unsigned int p1 = (unsigned)f2bf(v0.z) | ((unsigned)f2bf(v0.w) << 16);
                const unsigned int p2 = (unsigned)f2bf(v1.x) | ((unsigned)f2bf(v1.y) << 16);
                const unsigned int p3 = (unsigned)f2bf(v1.z) | ((unsigned)f2bf(v1.w) << 16);
                *(uint4*)dst = make_uint4(p0, p1, p2, p3);
            } else {
                const unsigned short* Ab = (const unsigned short*)Av + grow * K + k0 + fk;
                *(uint4*)dst = *(const uint4*)Ab;
            }
        }
        // ---- stage B (sub-tiles sr, sr+4) ----
        #pragma unroll
        for (int rr = 0; rr < 2; ++rr) {
            const int s = sr + rr * 4;
            const size_t gn = (size_t)(bn + s * 16 + fr);
            *(uint4*)&sB[s * 512 + lane * 8] = *(const uint4*)(Bt + gn * K + k0 + fk);
        }
        __syncthreads();

        short8 af[4], bfr[4];
        #pragma unroll
        for (int i = 0; i < 4; ++i)
            af[i] = *(const short8*)&sA[(wm * 4 + i) * 512 + lane * 8];
        #pragma unroll
        for (int j = 0; j < 4; ++j)
            bfr[j] = *(const short8*)&sB[(wn * 4 + j) * 512 + lane * 8];
        #pragma unroll
        for (int i = 0; i < 4; ++i)
            #pragma unroll
            for (int j = 0; j < 4; ++j)
                acc[i][j] = __builtin_amdgcn_mfma_f32_16x16x32_bf16(
                    af[i], bfr[j], acc[i][j], 0, 0, 0);
        __syncthreads();
    }

    // ---- epilogue: C/D layout col = lane&15, row = (lane>>4)*4 + reg ----
    const int r0 = (lane >> 4) * 4;
    const int c0 = lane & 15;
    #pragma unroll
    for (int j = 0; j < 4; ++j) {
        const int col = bn + wn * 64 + j * 16 + c0;
        const float bj = bias ? bias[col] : 0.f;
        #pragma unroll
        for (int i = 0; i < 4; ++i) {
            #pragma unroll
            for (int r = 0; r < 4; ++r) {
                const int row = bm + wm * 64 + i * 16 + r0 + r;
                float v = acc[i][j][r] + bj;
                if (relu) v = fmaxf(v, 0.f);
                if (mask && mask[row]) v = 0.f;
                if (Cf) Cf[(size_t)row * N + col] = v;
                if (Cb) Cb[(size_t)row * N + col] = f2bf(v);
            }
        }
    }
}

// ---------------------------------------------------------------------------
// Weight transpose + cast: W[K][N] f32 -> Wt[N][K] bf16. K,N multiples of 32.
// ---------------------------------------------------------------------------
__global__ void transpose_cast(const float* __restrict__ W,
                               unsigned short* __restrict__ Wt, int K, int N)
{
    __shared__ float t[32][33];
    const int k0 = blockIdx.x * 32, n0 = blockIdx.y * 32;
    const int tx = threadIdx.x, ty = threadIdx.y;   // 32 x 8
    #pragma unroll
    for (int i = 0; i < 32; i += 8)
        t[ty + i][tx] = W[(size_t)(k0 + ty + i) * N + n0 + tx];
    __syncthreads();
    #pragma unroll
    for (int i = 0; i < 32; i += 8)
        Wt[(size_t)(n0 + ty + i) * K + k0 + tx] = f2bf(t[tx][ty + i]);
}

// ---------------------------------------------------------------------------
// Fused per-head softmax + bilinear deformable sampling (value in bf16).
// ---------------------------------------------------------------------------
__global__ __launch_bounds__(256) void sample_kernel(
    const unsigned short* __restrict__ value, const float* __restrict__ offb,
    const float* __restrict__ attnb, const float* __restrict__ ref,
    const int* __restrict__ sshapes, const int* __restrict__ lstart,
    unsigned short* __restrict__ samp)
{
    __shared__ float s_w[128][4];
    __shared__ int   s_i[128][4];
    __shared__ float s_a[128];

    const int i = blockIdx.x;
    const int b = i / LTOK;
    const int t = threadIdx.x;

    if (t < 128) {
        const int h  = t >> 4;
        const int p  = t & 15;
        const int l  = p >> 2;
        const int pp = p & 3;
        const int H = sshapes[2 * l], W = sshapes[2 * l + 1];
        const float Wf = (float)W, Hf = (float)H;

        const float ox = offb[(size_t)i * 256 + h * 32 + l * 8 + pp * 2 + 0];
        const float oy = offb[(size_t)i * 256 + h * 32 + l * 8 + pp * 2 + 1];
        const float rx = ref[(size_t)i * 8 + l * 2 + 0];
        const float ry = ref[(size_t)i * 8 + l * 2 + 1];

        const float x = (rx + ox / Wf) * Wf - 0.5f;
        const float y = (ry + oy / Hf) * Hf - 0.5f;
        const float x0 = floorf(x), y0 = floorf(y);
        const float dx = x - x0, dy = y - y0;
        const int x0i = (int)x0, y0i = (int)y0;
        const int s = lstart[l];

        const float cw[4] = {(1.f - dx) * (1.f - dy), dx * (1.f - dy),
                             (1.f - dx) * dy,         dx * dy};
        const int cx[4] = {x0i, x0i + 1, x0i,     x0i + 1};
        const int cy[4] = {y0i, y0i,     y0i + 1, y0i + 1};
        #pragma unroll
        for (int c = 0; c < 4; ++c) {
            const bool valid = (cx[c] >= 0) & (cx[c] < W) & (cy[c] >= 0) & (cy[c] < H);
            const int xi = min(max(cx[c], 0), W - 1);
            const int yi = min(max(cy[c], 0), H - 1);
            s_i[t][c] = s + yi * W + xi;
            s_w[t][c] = valid ? cw[c] : 0.f;
        }

        const float a = attnb[(size_t)i * 128 + t];
        float mx = a;
        #pragma unroll
        for (int m = 8; m; m >>= 1) mx = fmaxf(mx, __shfl_xor(mx, m, 16));
        const float e = __expf(a - mx);
        float ssum = e;
        #pragma unroll
        for (int m = 8; m; m >>= 1) ssum += __shfl_xor(ssum, m, 16);
        s_a[t] = e / ssum;
    }
    __syncthreads();

    const int h = t >> 5;
    const int d = t & 31;
    const size_t vbase = ((size_t)b * LTOK) * 256 + h * 32 + d;
    float acc = 0.f;
    #pragma unroll
    for (int p = 0; p < 16; ++p) {
        const int sl = h * 16 + p;
        const float aw = s_a[sl];
        #pragma unroll
        for (int c = 0; c < 4; ++c) {
            const float w = s_w[sl][c] * aw;
            const int idx = s_i[sl][c];
            acc = fmaf(w, bf2f(value[vbase + (size_t)idx * 256]), acc);
        }
    }
    samp[(size_t)i * 256 + t] = f2bf(acc);
}

// ---------------------------------------------------------------------------
// LayerNorm over D=256: out = LN(a + b) * g + be. One wave per token.
// ---------------------------------------------------------------------------
__global__ __launch_bounds__(256) void ln_kernel(
    const float* __restrict__ a, const float* __restrict__ b,
    const float* __restrict__ g, const float* __restrict__ be,
    float* __restrict__ out)
{
    const int wid  = threadIdx.x >> 6;
    const int lane = threadIdx.x & 63;
    const int tok  = blockIdx.x * 4 + wid;
    const size_t base = (size_t)tok * 256 + lane * 4;

    const float4 va = *(const float4*)(a + base);
    const float4 vb = *(const float4*)(b + base);
    float4 v;
    v.x = va.x + vb.x; v.y = va.y + vb.y; v.z = va.z + vb.z; v.w = va.w + vb.w;

    float s  = v.x + v.y + v.z + v.w;
    float sq = v.x * v.x + v.y * v.y + v.z * v.z + v.w * v.w;
    #pragma unroll
    for (int m = 32; m; m >>= 1) {
        s  += __shfl_xor(s, m, 64);
        sq += __shfl_xor(sq, m, 64);
    }
    const float mean = s * (1.f / 256.f);
    const float var  = sq * (1.f / 256.f) - mean * mean;
    const float rs   = rsqrtf(var + 1e-5f);

    const float4 g4 = *(const float4*)(g + lane * 4);
    const float4 b4 = *(const float4*)(be + lane * 4);
    float4 o;
    o.x = (v.x - mean) * rs * g4.x + b4.x;
    o.y = (v.y - mean) * rs * g4.y + b4.y;
    o.z = (v.z - mean) * rs * g4.z + b4.z;
    o.w = (v.w - mean) * rs * g4.w + b4.w;
    *(float4*)(out + base) = o;
}

// ---------------------------------------------------------------------------
extern "C" void kernel_launch(void* const* d_in, const int* in_sizes, int n_in,
                              void* d_out, int out_size, void* d_ws, size_t ws_size,
                              hipStream_t stream)
{
    const float* src   = (const float*)d_in[0];
    const float* pos   = (const float*)d_in[1];
    const float* ref   = (const float*)d_in[2];
    const int*   sshap = (const int*)d_in[3];
    const int*   lstrt = (const int*)d_in[4];
    const unsigned char* mask = (const unsigned char*)d_in[5];
    const float* w_off = (const float*)d_in[6];
    const float* b_off = (const float*)d_in[7];
    const float* w_att = (const float*)d_in[8];
    const float* b_att = (const float*)d_in[9];
    const float* w_val = (const float*)d_in[10];
    const float* b_val = (const float*)d_in[11];
    const float* w_out = (const float*)d_in[12];
    const float* b_out = (const float*)d_in[13];
    const float* ln1g  = (const float*)d_in[14];
    const float* ln1b  = (const float*)d_in[15];
    const float* w1    = (const float*)d_in[16];
    const float* b1    = (const float*)d_in[17];
    const float* w2    = (const float*)d_in[18];
    const float* b2    = (const float*)d_in[19];
    const float* ln2g  = (const float*)d_in[20];
    const float* ln2b  = (const float*)d_in[21];
    float* out = (float*)d_out;

    // workspace layout (bytes); SZB = NTOK*256*4 = 44.56 MB; total ~135 MB
    const size_t SZB = (size_t)NTOK * 256 * 4;
    char* w = (char*)d_ws;
    float*          buf0   = (float*)w;                          // off -> attn_out -> ffn_out
    unsigned short* vb16   = (unsigned short*)(w + SZB);         // value bf16 (SZB/2)
    float*          attnf  = (float*)(w + SZB + SZB / 2);        // attn logits (SZB/2)
    float*          xf     = (float*)(w + SZB);                  // x after LN1 (reuses vb16+attnf)
    unsigned short* samp16 = (unsigned short*)(w + 2 * SZB);     // sampled bf16 (SZB/2)
    unsigned short* hb     = (unsigned short*)(w + 2 * SZB + SZB / 2); // FFN hidden chunk (SZB/2)
    unsigned short* wvalT  = (unsigned short*)(w + 3 * SZB);
    unsigned short* woffT  = wvalT + 256 * 256;
    unsigned short* wattT  = woffT + 256 * 256;
    unsigned short* woutT  = wattT + 128 * 256;
    unsigned short* w1T    = woutT + 256 * 256;
    unsigned short* w2T    = w1T + 1024 * 256;

    const dim3 blk(256);
    const dim3 tblk(32, 8);

    // weights -> bf16 transposed [N][K]
    transpose_cast<<<dim3(8, 8),  tblk, 0, stream>>>(w_val, wvalT, 256, 256);
    transpose_cast<<<dim3(8, 8),  tblk, 0, stream>>>(w_off, woffT, 256, 256);
    transpose_cast<<<dim3(8, 4),  tblk, 0, stream>>>(w_att, wattT, 256, 128);
    transpose_cast<<<dim3(8, 8),  tblk, 0, stream>>>(w_out, woutT, 256, 256);
    transpose_cast<<<dim3(8, 32), tblk, 0, stream>>>(w1,    w1T,   256, 1024);
    transpose_cast<<<dim3(32, 8), tblk, 0, stream>>>(w2,    w2T,   1024, 256);

    // value = src @ w_val + b_val (masked) -> bf16
    gemm_mfma<<<dim3(2, NTOK / TM), blk, 0, stream>>>(
        src, nullptr, wvalT, b_val, nullptr, vb16, NTOK, 256, 256, 0, 0, mask);
    // off = (src+pos) @ w_off + b_off -> f32
    gemm_mfma<<<dim3(2, NTOK / TM), blk, 0, stream>>>(
        src, pos, woffT, b_off, buf0, nullptr, NTOK, 256, 256, 0, 0, nullptr);
    // attn logits = (src+pos) @ w_attn + b_attn -> f32
    gemm_mfma<<<dim3(1, NTOK / TM), blk, 0, stream>>>(
        src, pos, wattT, b_att, attnf, nullptr, NTOK, 128, 256, 0, 0, nullptr);

    // softmax + bilinear sampling -> samp16
    sample_kernel<<<dim3(NTOK), blk, 0, stream>>>(
        vb16, buf0, attnf, ref, sshap, lstrt, samp16);

    // attn_out = samp @ w_out + b_out -> buf0 (off dead)
    gemm_mfma<<<dim3(2, NTOK / TM), blk, 0, stream>>>(
        samp16, nullptr, woutT, b_out, buf0, nullptr, NTOK, 256, 256, 1, 0, nullptr);

    // x = LN1(src + attn_out) -> xf (vb16/attnf dead)
    ln_kernel<<<dim3(NTOK / 4), blk, 0, stream>>>(src, buf0, ln1g, ln1b, xf);

    // FFN, 4 token chunks; hidden bf16 chunk reuses hb
    const int CH = NTOK / 4;   // 10880 = 128 * 85
    for (int c = 0; c < 4; ++c) {
        const float* xc = xf + (size_t)c * CH * 256;
        float* fc = buf0 + (size_t)c * CH * 256;
        gemm_mfma<<<dim3(8, CH / TM), blk, 0, stream>>>(
            xc, nullptr, w1T, b1, nullptr, hb, CH, DFFN, 256, 0, 1, nullptr);
        gemm_mfma<<<dim3(2, CH / TM), blk, 0, stream>>>(
            hb, nullptr, w2T, b2, fc, nullptr, CH, 256, DFFN, 1, 0, nullptr);
    }

    // out = LN2(x + ffn)
    ln_kernel<<<dim3(NTOK / 4), blk, 0, stream>>>(xf, buf0, ln2g, ln2b, out);
}

// Round 4
// 711.005 us; speedup vs baseline: 2.3119x; 1.0069x over previous
//
#include <hip/hip_runtime.h>
#include <hip/hip_bf16.h>

// Problem constants
#define BSZ      2
#define LTOK     21760            // 128*128 + 64*64 + 32*32 + 16*16
#define NTOK     (BSZ * LTOK)     // 43520 = 128 * 340
#define DMODEL   256
#define DFFN     1024

typedef __attribute__((ext_vector_type(8))) short short8;   // 8 bf16 = 4 VGPRs
typedef __attribute__((ext_vector_type(4))) float f32x4;

__device__ __forceinline__ unsigned short f2bf(float x) {
    __hip_bfloat16 h = __float2bfloat16(x);
    return *reinterpret_cast<unsigned short*>(&h);
}
__device__ __forceinline__ float bf2f(unsigned short u) {
    union { unsigned int i; float f; } c; c.i = ((unsigned int)u) << 16; return c.f;
}

// ---------------------------------------------------------------------------
// bf16 MFMA GEMM:  C[M x N] = A @ Bt^T (+bias) with Bt = [N][K] bf16.
// 128x128 tile, BK=32, 4 waves 2x2, each wave 4x4 tiles of 16x16x32.
// LDS in MFMA fragment order (64 x 16 B slots per 16x32 sub-tile).
// amode 0: A f32 [M][K] (+optional A2), cast in staging.  amode 1: A bf16.
// cmode 0: row-major write (Cf f32 and/or Cb bf16).
// cmode 1: head-major "vT" write: Cb[((b*8+h)*LTOK+s)*32+d], h=col>>5,d=col&31.
// ---------------------------------------------------------------------------
#define TM 128
#define TN 128
#define TBK 32

__global__ __launch_bounds__(256) void gemm_mfma(
    const void* __restrict__ Av, const float* __restrict__ A2,
    const unsigned short* __restrict__ Bt, const float* __restrict__ bias,
    float* __restrict__ Cf, unsigned short* __restrict__ Cb,
    int M, int N, int K, int amode, int relu, int cmode,
    const unsigned char* __restrict__ mask)
{
    __shared__ __align__(16) unsigned short sA[TM * TBK];   // 8 KB
    __shared__ __align__(16) unsigned short sB[TN * TBK];   // 8 KB

    const int tid  = threadIdx.x;
    const int lane = tid & 63;
    const int wave = tid >> 6;
    const int wm = wave >> 1, wn = wave & 1;

    const int bm = blockIdx.y * TM;
    const int bn = blockIdx.x * TN;

    const int sr = tid >> 6;           // staging sub-tile base (0..3)
    const int fr = lane & 15;          // row within sub-tile
    const int fk = (lane >> 4) * 8;    // k offset (0,8,16,24)

    f32x4 acc[4][4];
    #pragma unroll
    for (int i = 0; i < 4; ++i)
        #pragma unroll
        for (int j = 0; j < 4; ++j)
            acc[i][j] = (f32x4){0.f, 0.f, 0.f, 0.f};

    for (int k0 = 0; k0 < K; k0 += TBK) {
        #pragma unroll
        for (int rr = 0; rr < 2; ++rr) {
            const int s = sr + rr * 4;
            const size_t grow = (size_t)(bm + s * 16 + fr);
            unsigned short* dst = &sA[s * 512 + lane * 8];
            if (amode == 0) {
                const float* Af = (const float*)Av + grow * K + k0 + fk;
                float4 v0 = *(const float4*)Af;
                float4 v1 = *(const float4*)(Af + 4);
                if (A2) {
                    const float* Pf = A2 + grow * K + k0 + fk;
                    const float4 p0 = *(const float4*)Pf;
                    const float4 p1 = *(const float4*)(Pf + 4);
                    v0.x += p0.x; v0.y += p0.y; v0.z += p0.z; v0.w += p0.w;
                    v1.x += p1.x; v1.y += p1.y; v1.z += p1.z; v1.w += p1.w;
                }
                const unsigned int p0 = (unsigned)f2bf(v0.x) | ((unsigned)f2bf(v0.y) << 16);
                const unsigned int p1 = (unsigned)f2bf(v0.z) | ((unsigned)f2bf(v0.w) << 16);
                const unsigned int p2 = (unsigned)f2bf(v1.x) | ((unsigned)f2bf(v1.y) << 16);
                const unsigned int p3 = (unsigned)f2bf(v1.z) | ((unsigned)f2bf(v1.w) << 16);
                *(uint4*)dst = make_uint4(p0, p1, p2, p3);
            } else {
                const unsigned short* Ab = (const unsigned short*)Av + grow * K + k0 + fk;
                *(uint4*)dst = *(const uint4*)Ab;
            }
        }
        #pragma unroll
        for (int rr = 0; rr < 2; ++rr) {
            const int s = sr + rr * 4;
            const size_t gn = (size_t)(bn + s * 16 + fr);
            *(uint4*)&sB[s * 512 + lane * 8] = *(const uint4*)(Bt + gn * K + k0 + fk);
        }
        __syncthreads();

        short8 af[4], bfr[4];
        #pragma unroll
        for (int i = 0; i < 4; ++i)
            af[i] = *(const short8*)&sA[(wm * 4 + i) * 512 + lane * 8];
        #pragma unroll
        for (int j = 0; j < 4; ++j)
            bfr[j] = *(const short8*)&sB[(wn * 4 + j) * 512 + lane * 8];
        #pragma unroll
        for (int i = 0; i < 4; ++i)
            #pragma unroll
            for (int j = 0; j < 4; ++j)
                acc[i][j] = __builtin_amdgcn_mfma_f32_16x16x32_bf16(
                    af[i], bfr[j], acc[i][j], 0, 0, 0);
        __syncthreads();
    }

    // C/D layout: col = lane&15, row = (lane>>4)*4 + reg
    const int r0 = (lane >> 4) * 4;
    const int c0 = lane & 15;
    #pragma unroll
    for (int j = 0; j < 4; ++j) {
        const int col = bn + wn * 64 + j * 16 + c0;
        const float bj = bias ? bias[col] : 0.f;
        #pragma unroll
        for (int i = 0; i < 4; ++i) {
            #pragma unroll
            for (int r = 0; r < 4; ++r) {
                const int row = bm + wm * 64 + i * 16 + r0 + r;
                float v = acc[i][j][r] + bj;
                if (relu) v = fmaxf(v, 0.f);
                if (mask && mask[row]) v = 0.f;
                if (cmode == 1) {
                    const int bb = row >= LTOK;
                    const int srow = row - bb * LTOK;
                    const int h = col >> 5, d = col & 31;
                    Cb[((size_t)(bb * 8 + h) * LTOK + srow) * 32 + d] = f2bf(v);
                } else {
                    if (Cf) Cf[(size_t)row * N + col] = v;
                    if (Cb) Cb[(size_t)row * N + col] = f2bf(v);
                }
            }
        }
    }
}

// ---------------------------------------------------------------------------
// Weight transpose + cast: W[K][N] f32 -> Wt[N][K] bf16 (K,N mult of 32)
// ---------------------------------------------------------------------------
__global__ void transpose_cast(const float* __restrict__ W,
                               unsigned short* __restrict__ Wt, int K, int N)
{
    __shared__ float t[32][33];
    const int k0 = blockIdx.x * 32, n0 = blockIdx.y * 32;
    const int tx = threadIdx.x, ty = threadIdx.y;   // 32 x 8
    #pragma unroll
    for (int i = 0; i < 32; i += 8)
        t[ty + i][tx] = W[(size_t)(k0 + ty + i) * N + n0 + tx];
    __syncthreads();
    #pragma unroll
    for (int i = 0; i < 32; i += 8)
        Wt[(size_t)(n0 + ty + i) * K + k0 + tx] = f2bf(t[tx][ty + i]);
}

__global__ void concat_bias(const float* __restrict__ b_off,
                            const float* __restrict__ b_att,
                            float* __restrict__ dst)
{
    const int t = threadIdx.x;   // 384 threads
    dst[t] = (t < 256) ? b_off[t] : b_att[t - 256];
}

// ---------------------------------------------------------------------------
// Fused softmax + bilinear sampling, head-major value.
// Block = one (plane, 16-token chunk); plane = blockIdx % 16 (= b*8+h) so a
// plane stays on one XCD (round-robin dispatch); per-XCD gather working set
// = 2 planes = 2.7 MB < 4 MB L2.
// Grid = 16 * (LTOK/16) = NTOK/2 blocks.
// Phase A: 256 threads = 16 tokens x 16 points. Phase B: 8 tokens x 32 dims x2.
// ---------------------------------------------------------------------------
__global__ __launch_bounds__(256) void sample_kernel(
    const unsigned short* __restrict__ vT, const float* __restrict__ qp,
    const float* __restrict__ ref,
    const int* __restrict__ sshapes, const int* __restrict__ lstart,
    unsigned short* __restrict__ samp)
{
    __shared__ float s_w[256][4];
    __shared__ int   s_i[256][4];
    __shared__ float s_a[256];

    const int blk   = blockIdx.x;
    const int plane = blk & 15;
    const int chunk = blk >> 4;              // 0 .. LTOK/16-1
    const int b = plane >> 3;
    const int h = plane & 7;
    const int s0 = chunk * 16;               // token offset within plane
    const int t = threadIdx.x;

    // ---- phase A: per (token, point) ----
    {
        const int tl = t >> 4;               // 0..15 token in chunk
        const int p  = t & 15;
        const int l  = p >> 2;
        const int pp = p & 3;
        const int H = sshapes[2 * l], W = sshapes[2 * l + 1];
        const float Wf = (float)W, Hf = (float)H;
        const size_t tok = (size_t)(b * LTOK + s0 + tl);

        const float ox = qp[tok * 384 + h * 32 + l * 8 + pp * 2 + 0];
        const float oy = qp[tok * 384 + h * 32 + l * 8 + pp * 2 + 1];
        const float rx = ref[tok * 8 + l * 2 + 0];
        const float ry = ref[tok * 8 + l * 2 + 1];

        const float x = (rx + ox / Wf) * Wf - 0.5f;
        const float y = (ry + oy / Hf) * Hf - 0.5f;
        const float x0 = floorf(x), y0 = floorf(y);
        const float dx = x - x0, dy = y - y0;
        const int x0i = (int)x0, y0i = (int)y0;
        const int s = lstart[l];

        const float cw[4] = {(1.f - dx) * (1.f - dy), dx * (1.f - dy),
                             (1.f - dx) * dy,         dx * dy};
        const int cx[4] = {x0i, x0i + 1, x0i,     x0i + 1};
        const int cy[4] = {y0i, y0i,     y0i + 1, y0i + 1};
        #pragma unroll
        for (int c = 0; c < 4; ++c) {
            const bool valid = (cx[c] >= 0) & (cx[c] < W) & (cy[c] >= 0) & (cy[c] < H);
            const int xi = min(max(cx[c], 0), W - 1);
            const int yi = min(max(cy[c], 0), H - 1);
            s_i[t][c] = s + yi * W + xi;
            s_w[t][c] = valid ? cw[c] : 0.f;
        }

        const float a = qp[tok * 384 + 256 + h * 16 + p];
        float mx = a;
        #pragma unroll
        for (int m = 8; m; m >>= 1) mx = fmaxf(mx, __shfl_xor(mx, m, 16));
        const float e = __expf(a - mx);
        float ssum = e;
        #pragma unroll
        for (int m = 8; m; m >>= 1) ssum += __shfl_xor(ssum, m, 16);
        s_a[t] = e / ssum;
    }
    __syncthreads();

    // ---- phase B: gather-accumulate ----
    const int d   = t & 31;
    const int sub = t >> 5;                  // 0..7
    const unsigned short* vp = vT + (size_t)plane * LTOK * 32;
    #pragma unroll
    for (int it = 0; it < 2; ++it) {
        const int tl = it * 8 + sub;
        float acc = 0.f;
        #pragma unroll
        for (int p = 0; p < 16; ++p) {
            const int sl = tl * 16 + p;
            const float aw = s_a[sl];
            #pragma unroll
            for (int c = 0; c < 4; ++c) {
                const float w = s_w[sl][c] * aw;
                acc = fmaf(w, bf2f(vp[(size_t)s_i[sl][c] * 32 + d]), acc);
            }
        }
        samp[(size_t)(b * LTOK + s0 + tl) * 256 + h * 32 + d] = f2bf(acc);
    }
}

// ---------------------------------------------------------------------------
// LayerNorm over D=256: out = LN(a + b) * g + be. One wave per token.
// a may be f32 or bf16; outputs f32 and/or bf16.
// ---------------------------------------------------------------------------
__global__ __launch_bounds__(256) void ln_kernel(
    const void* __restrict__ a, int a_bf16, const float* __restrict__ b,
    const float* __restrict__ g, const float* __restrict__ be,
    float* __restrict__ outF, unsigned short* __restrict__ outB)
{
    const int wid  = threadIdx.x >> 6;
    const int lane = threadIdx.x & 63;
    const int tok  = blockIdx.x * 4 + wid;
    const size_t base = (size_t)tok * 256 + lane * 4;

    float4 va;
    if (a_bf16) {
        const ushort4 u = *(const ushort4*)((const unsigned short*)a + base);
        va.x = bf2f(u.x); va.y = bf2f(u.y); va.z = bf2f(u.z); va.w = bf2f(u.w);
    } else {
        va = *(const float4*)((const float*)a + base);
    }
    const float4 vb = *(const float4*)(b + base);
    float4 v;
    v.x = va.x + vb.x; v.y = va.y + vb.y; v.z = va.z + vb.z; v.w = va.w + vb.w;

    float s  = v.x + v.y + v.z + v.w;
    float sq = v.x * v.x + v.y * v.y + v.z * v.z + v.w * v.w;
    #pragma unroll
    for (int m = 32; m; m >>= 1) {
        s  += __shfl_xor(s, m, 64);
        sq += __shfl_xor(sq, m, 64);
    }
    const float mean = s * (1.f / 256.f);
    const float var  = sq * (1.f / 256.f) - mean * mean;
    const float rs   = rsqrtf(var + 1e-5f);

    const float4 g4 = *(const float4*)(g + lane * 4);
    const float4 b4 = *(const float4*)(be + lane * 4);
    float4 o;
    o.x = (v.x - mean) * rs * g4.x + b4.x;
    o.y = (v.y - mean) * rs * g4.y + b4.y;
    o.z = (v.z - mean) * rs * g4.z + b4.z;
    o.w = (v.w - mean) * rs * g4.w + b4.w;
    if (outF) *(float4*)(outF + base) = o;
    if (outB) {
        ushort4 u;
        u.x = f2bf(o.x); u.y = f2bf(o.y); u.z = f2bf(o.z); u.w = f2bf(o.w);
        *(ushort4*)(outB + base) = u;
    }
}

// ---------------------------------------------------------------------------
extern "C" void kernel_launch(void* const* d_in, const int* in_sizes, int n_in,
                              void* d_out, int out_size, void* d_ws, size_t ws_size,
                              hipStream_t stream)
{
    const float* src   = (const float*)d_in[0];
    const float* pos   = (const float*)d_in[1];
    const float* ref   = (const float*)d_in[2];
    const int*   sshap = (const int*)d_in[3];
    const int*   lstrt = (const int*)d_in[4];
    const unsigned char* mask = (const unsigned char*)d_in[5];
    const float* w_off = (const float*)d_in[6];
    const float* b_off = (const float*)d_in[7];
    const float* w_att = (const float*)d_in[8];
    const float* b_att = (const float*)d_in[9];
    const float* w_val = (const float*)d_in[10];
    const float* b_val = (const float*)d_in[11];
    const float* w_out = (const float*)d_in[12];
    const float* b_out = (const float*)d_in[13];
    const float* ln1g  = (const float*)d_in[14];
    const float* ln1b  = (const float*)d_in[15];
    const float* w1    = (const float*)d_in[16];
    const float* b1    = (const float*)d_in[17];
    const float* w2    = (const float*)d_in[18];
    const float* b2    = (const float*)d_in[19];
    const float* ln2g  = (const float*)d_in[20];
    const float* ln2b  = (const float*)d_in[21];
    float* out = (float*)d_out;

    // ---- workspace layout (all regions disjoint in time where live) ----
    // [0,        1.5 SZB)  qpf  (f32 [NTOK][384])     -> later aof, ffo (f32 [NTOK][256])
    // [1.5 SZB,  2.0 SZB)  vT   (bf16 head-major)
    // [2.0 SZB,  2.5 SZB)  samp16 (bf16)              -> later hb (FFN hidden chunk)
    // [2.5 SZB,  3.0 SZB)  xb   (bf16)
    // [3.0 SZB,  +1.5 MB)  weights bf16 + bias concat
    const size_t SZB  = (size_t)NTOK * 256 * 4;       // 44.56 MB
    const size_t HSZB = SZB / 2;                      // 22.28 MB
    char* w = (char*)d_ws;
    float*          qpf    = (float*)w;
    float*          aof    = (float*)w;
    float*          ffo    = (float*)w;
    unsigned short* vT     = (unsigned short*)(w + SZB * 3 / 2);
    unsigned short* samp16 = (unsigned short*)(w + SZB * 2);
    unsigned short* hb     = samp16;                  // reuse after samp dead
    unsigned short* xb     = (unsigned short*)(w + SZB * 2 + HSZB);
    char* wreg = w + SZB * 3;
    unsigned short* wvalT  = (unsigned short*)wreg;
    unsigned short* woaT   = wvalT + 256 * 256;       // [384][256]
    unsigned short* woutT  = woaT + 384 * 256;
    unsigned short* w1T    = woutT + 256 * 256;
    unsigned short* w2T    = w1T + 1024 * 256;
    float*          bcat   = (float*)(w2T + 256 * 1024);

    const dim3 blk(256);
    const dim3 tblk(32, 8);

    // weights -> bf16 transposed [N][K]
    transpose_cast<<<dim3(8, 8),  tblk, 0, stream>>>(w_val, wvalT, 256, 256);
    transpose_cast<<<dim3(8, 8),  tblk, 0, stream>>>(w_off, woaT,  256, 256);
    transpose_cast<<<dim3(8, 4),  tblk, 0, stream>>>(w_att, woaT + 256 * 256, 256, 128);
    transpose_cast<<<dim3(8, 8),  tblk, 0, stream>>>(w_out, woutT, 256, 256);
    transpose_cast<<<dim3(8, 32), tblk, 0, stream>>>(w1,    w1T,   256, 1024);
    transpose_cast<<<dim3(32, 8), tblk, 0, stream>>>(w2,    w2T,   1024, 256);
    concat_bias<<<1, 384, 0, stream>>>(b_off, b_att, bcat);

    // value = src @ w_val + b_val (masked) -> vT head-major bf16
    gemm_mfma<<<dim3(2, NTOK / TM), blk, 0, stream>>>(
        src, nullptr, wvalT, b_val, nullptr, vT, NTOK, 256, 256, 0, 0, 1, mask);
    // qproj = (src+pos) @ [w_off|w_att] + [b_off|b_att] -> qpf f32 [NTOK][384]
    gemm_mfma<<<dim3(3, NTOK / TM), blk, 0, stream>>>(
        src, pos, woaT, bcat, qpf, nullptr, NTOK, 384, 256, 0, 0, 0, nullptr);

    // softmax + bilinear sampling -> samp16. Grid = 16 planes * LTOK/16 chunks.
    sample_kernel<<<dim3(16 * (LTOK / 16)), blk, 0, stream>>>(
        vT, qpf, ref, sshap, lstrt, samp16);

    // attn_out = samp @ w_out + b_out -> aof (qpf dead)
    gemm_mfma<<<dim3(2, NTOK / TM), blk, 0, stream>>>(
        samp16, nullptr, woutT, b_out, aof, nullptr, NTOK, 256, 256, 1, 0, 0, nullptr);

    // x = LN1(src + attn_out) -> xb bf16
    ln_kernel<<<dim3(NTOK / 4), blk, 0, stream>>>(
        src, 0, aof, ln1g, ln1b, nullptr, xb);

    // FFN, 4 token chunks; hidden bf16 chunk reuses samp16 region (samp dead)
    const int CH = NTOK / 4;   // 10880 = 128 * 85
    for (int c = 0; c < 4; ++c) {
        const unsigned short* xc = xb + (size_t)c * CH * 256;
        float* fc = ffo + (size_t)c * CH * 256;
        gemm_mfma<<<dim3(8, CH / TM), blk, 0, stream>>>(
            xc, nullptr, w1T, b1, nullptr, hb, CH, DFFN, 256, 1, 1, 0, nullptr);
        gemm_mfma<<<dim3(2, CH / TM), blk, 0, stream>>>(
            hb, nullptr, w2T, b2, fc, nullptr, CH, 256, DFFN, 1, 0, 0, nullptr);
    }

    // out = LN2(x + ffn)
    ln_kernel<<<dim3(NTOK / 4), blk, 0, stream>>>(
        xb, 1, ffo, ln2g, ln2b, out, nullptr);
}

// Round 5
// 547.607 us; speedup vs baseline: 3.0018x; 1.2984x over previous
//
#include <hip/hip_runtime.h>
#include <hip/hip_bf16.h>

// Problem constants
#define BSZ      2
#define LTOK     21760            // 128*128 + 64*64 + 32*32 + 16*16
#define NTOK     (BSZ * LTOK)     // 43520 = 128 * 340
#define DMODEL   256
#define DFFN     1024

typedef __attribute__((ext_vector_type(8))) short short8;   // 8 bf16 = 4 VGPRs
typedef __attribute__((ext_vector_type(4))) float f32x4;

__device__ __forceinline__ unsigned short f2bf(float x) {
    __hip_bfloat16 h = __float2bfloat16(x);
    return *reinterpret_cast<unsigned short*>(&h);
}
__device__ __forceinline__ float bf2f(unsigned short u) {
    union { unsigned int i; float f; } c; c.i = ((unsigned int)u) << 16; return c.f;
}
__device__ __forceinline__ float bflo(unsigned int u) {
    union { unsigned int i; float f; } c; c.i = u << 16; return c.f;
}
__device__ __forceinline__ float bfhi(unsigned int u) {
    union { unsigned int i; float f; } c; c.i = u & 0xffff0000u; return c.f;
}

// ---------------------------------------------------------------------------
// bf16 MFMA GEMM:  C[M x N] = A @ Bt^T (+bias) with Bt = [N][K] bf16.
// 128x128 tile, BK=32, 4 waves 2x2, each wave 4x4 tiles of 16x16x32.
// LDS in MFMA fragment order (64 x 16 B slots per 16x32 sub-tile).
// amode 0: A f32 [M][K] (+optional A2), cast in staging.  amode 1: A bf16.
// cmode 0: row-major write (Cf f32 and/or Cb bf16).
// cmode 1: head-major "vT" write: Cb[((b*8+h)*LTOK+s)*32+d], h=col>>5,d=col&31.
// ---------------------------------------------------------------------------
#define TM 128
#define TN 128
#define TBK 32

__global__ __launch_bounds__(256) void gemm_mfma(
    const void* __restrict__ Av, const float* __restrict__ A2,
    const unsigned short* __restrict__ Bt, const float* __restrict__ bias,
    float* __restrict__ Cf, unsigned short* __restrict__ Cb,
    int M, int N, int K, int amode, int relu, int cmode,
    const unsigned char* __restrict__ mask)
{
    __shared__ __align__(16) unsigned short sA[TM * TBK];   // 8 KB
    __shared__ __align__(16) unsigned short sB[TN * TBK];   // 8 KB

    const int tid  = threadIdx.x;
    const int lane = tid & 63;
    const int wave = tid >> 6;
    const int wm = wave >> 1, wn = wave & 1;

    const int bm = blockIdx.y * TM;
    const int bn = blockIdx.x * TN;

    const int sr = tid >> 6;           // staging sub-tile base (0..3)
    const int fr = lane & 15;          // row within sub-tile
    const int fk = (lane >> 4) * 8;    // k offset (0,8,16,24)

    f32x4 acc[4][4];
    #pragma unroll
    for (int i = 0; i < 4; ++i)
        #pragma unroll
        for (int j = 0; j < 4; ++j)
            acc[i][j] = (f32x4){0.f, 0.f, 0.f, 0.f};

    for (int k0 = 0; k0 < K; k0 += TBK) {
        #pragma unroll
        for (int rr = 0; rr < 2; ++rr) {
            const int s = sr + rr * 4;
            const size_t grow = (size_t)(bm + s * 16 + fr);
            unsigned short* dst = &sA[s * 512 + lane * 8];
            if (amode == 0) {
                const float* Af = (const float*)Av + grow * K + k0 + fk;
                float4 v0 = *(const float4*)Af;
                float4 v1 = *(const float4*)(Af + 4);
                if (A2) {
                    const float* Pf = A2 + grow * K + k0 + fk;
                    const float4 p0 = *(const float4*)Pf;
                    const float4 p1 = *(const float4*)(Pf + 4);
                    v0.x += p0.x; v0.y += p0.y; v0.z += p0.z; v0.w += p0.w;
                    v1.x += p1.x; v1.y += p1.y; v1.z += p1.z; v1.w += p1.w;
                }
                const unsigned int p0 = (unsigned)f2bf(v0.x) | ((unsigned)f2bf(v0.y) << 16);
                const unsigned int p1 = (unsigned)f2bf(v0.z) | ((unsigned)f2bf(v0.w) << 16);
                const unsigned int p2 = (unsigned)f2bf(v1.x) | ((unsigned)f2bf(v1.y) << 16);
                const unsigned int p3 = (unsigned)f2bf(v1.z) | ((unsigned)f2bf(v1.w) << 16);
                *(uint4*)dst = make_uint4(p0, p1, p2, p3);
            } else {
                const unsigned short* Ab = (const unsigned short*)Av + grow * K + k0 + fk;
                *(uint4*)dst = *(const uint4*)Ab;
            }
        }
        #pragma unroll
        for (int rr = 0; rr < 2; ++rr) {
            const int s = sr + rr * 4;
            const size_t gn = (size_t)(bn + s * 16 + fr);
            *(uint4*)&sB[s * 512 + lane * 8] = *(const uint4*)(Bt + gn * K + k0 + fk);
        }
        __syncthreads();

        short8 af[4], bfr[4];
        #pragma unroll
        for (int i = 0; i < 4; ++i)
            af[i] = *(const short8*)&sA[(wm * 4 + i) * 512 + lane * 8];
        #pragma unroll
        for (int j = 0; j < 4; ++j)
            bfr[j] = *(const short8*)&sB[(wn * 4 + j) * 512 + lane * 8];
        #pragma unroll
        for (int i = 0; i < 4; ++i)
            #pragma unroll
            for (int j = 0; j < 4; ++j)
                acc[i][j] = __builtin_amdgcn_mfma_f32_16x16x32_bf16(
                    af[i], bfr[j], acc[i][j], 0, 0, 0);
        __syncthreads();
    }

    // C/D layout: col = lane&15, row = (lane>>4)*4 + reg
    const int r0 = (lane >> 4) * 4;
    const int c0 = lane & 15;
    #pragma unroll
    for (int j = 0; j < 4; ++j) {
        const int col = bn + wn * 64 + j * 16 + c0;
        const float bj = bias ? bias[col] : 0.f;
        #pragma unroll
        for (int i = 0; i < 4; ++i) {
            #pragma unroll
            for (int r = 0; r < 4; ++r) {
                const int row = bm + wm * 64 + i * 16 + r0 + r;
                float v = acc[i][j][r] + bj;
                if (relu) v = fmaxf(v, 0.f);
                if (mask && mask[row]) v = 0.f;
                if (cmode == 1) {
                    const int bb = row >= LTOK;
                    const int srow = row - bb * LTOK;
                    const int h = col >> 5, d = col & 31;
                    Cb[((size_t)(bb * 8 + h) * LTOK + srow) * 32 + d] = f2bf(v);
                } else {
                    if (Cf) Cf[(size_t)row * N + col] = v;
                    if (Cb) Cb[(size_t)row * N + col] = f2bf(v);
                }
            }
        }
    }
}

// ---------------------------------------------------------------------------
// Weight transpose + cast: W[K][N] f32 -> Wt[N][K] bf16 (K,N mult of 32)
// ---------------------------------------------------------------------------
__global__ void transpose_cast(const float* __restrict__ W,
                               unsigned short* __restrict__ Wt, int K, int N)
{
    __shared__ float t[32][33];
    const int k0 = blockIdx.x * 32, n0 = blockIdx.y * 32;
    const int tx = threadIdx.x, ty = threadIdx.y;   // 32 x 8
    #pragma unroll
    for (int i = 0; i < 32; i += 8)
        t[ty + i][tx] = W[(size_t)(k0 + ty + i) * N + n0 + tx];
    __syncthreads();
    #pragma unroll
    for (int i = 0; i < 32; i += 8)
        Wt[(size_t)(n0 + ty + i) * K + k0 + tx] = f2bf(t[tx][ty + i]);
}

__global__ void concat_bias(const float* __restrict__ b_off,
                            const float* __restrict__ b_att,
                            float* __restrict__ dst)
{
    const int t = threadIdx.x;   // 384 threads
    dst[t] = (t < 256) ? b_off[t] : b_att[t - 256];
}

// ---------------------------------------------------------------------------
// Fused softmax + bilinear sampling, head-major value.
// Block = (plane, 16-token chunk); plane = blockIdx % 16 pins a plane to one
// XCD (2 planes = 2.7 MB < 4 MB L2). Grid = 16 * (LTOK/16).
// Phase A: 256 threads = 16 tokens x 16 points; corner byte-offsets + weights
// (validity * bilinear * softmax-prob all folded) into LDS.
// Phase B: 256 threads = 16 tokens x 16 dim-pairs; u32 gathers (2 bf16/load),
// 64 loads/thread, one u32 store.
// ---------------------------------------------------------------------------
__global__ __launch_bounds__(256) void sample_kernel(
    const unsigned short* __restrict__ vT, const float* __restrict__ qp,
    const float* __restrict__ ref,
    const int* __restrict__ sshapes, const int* __restrict__ lstart,
    unsigned short* __restrict__ samp)
{
    __shared__ float s_w[256][4];
    __shared__ int   s_o[256][4];   // byte offsets into the plane

    const int blk   = blockIdx.x;
    const int plane = blk & 15;
    const int chunk = blk >> 4;              // 0 .. LTOK/16-1
    const int b = plane >> 3;
    const int h = plane & 7;
    const int s0 = chunk * 16;               // token offset within plane
    const int t = threadIdx.x;

    // ---- phase A: per (token, point) ----
    {
        const int tl = t >> 4;               // 0..15 token in chunk
        const int p  = t & 15;
        const int l  = p >> 2;
        const int pp = p & 3;
        const int H = sshapes[2 * l], W = sshapes[2 * l + 1];
        const float Wf = (float)W, Hf = (float)H;
        const size_t tok = (size_t)(b * LTOK + s0 + tl);

        const float ox = qp[tok * 384 + h * 32 + l * 8 + pp * 2 + 0];
        const float oy = qp[tok * 384 + h * 32 + l * 8 + pp * 2 + 1];
        const float rx = ref[tok * 8 + l * 2 + 0];
        const float ry = ref[tok * 8 + l * 2 + 1];

        const float x = (rx + ox / Wf) * Wf - 0.5f;
        const float y = (ry + oy / Hf) * Hf - 0.5f;
        const float x0 = floorf(x), y0 = floorf(y);
        const float dx = x - x0, dy = y - y0;
        const int x0i = (int)x0, y0i = (int)y0;
        const int s = lstart[l];

        // softmax prob over the 16 points of this head (16-lane groups)
        const float a = qp[tok * 384 + 256 + h * 16 + p];
        float mx = a;
        #pragma unroll
        for (int m = 8; m; m >>= 1) mx = fmaxf(mx, __shfl_xor(mx, m, 16));
        const float e = __expf(a - mx);
        float ssum = e;
        #pragma unroll
        for (int m = 8; m; m >>= 1) ssum += __shfl_xor(ssum, m, 16);
        const float prob = e / ssum;

        const float cw[4] = {(1.f - dx) * (1.f - dy), dx * (1.f - dy),
                             (1.f - dx) * dy,         dx * dy};
        const int cx[4] = {x0i, x0i + 1, x0i,     x0i + 1};
        const int cy[4] = {y0i, y0i,     y0i + 1, y0i + 1};
        #pragma unroll
        for (int c = 0; c < 4; ++c) {
            const bool valid = (cx[c] >= 0) & (cx[c] < W) & (cy[c] >= 0) & (cy[c] < H);
            const int xi = min(max(cx[c], 0), W - 1);
            const int yi = min(max(cy[c], 0), H - 1);
            s_o[t][c] = (s + yi * W + xi) * 64;          // byte offset (32 bf16)
            s_w[t][c] = valid ? cw[c] * prob : 0.f;
        }
    }
    __syncthreads();

    // ---- phase B: gather-accumulate, (token, dim-pair) ----
    const int tl = t >> 4;                   // 0..15
    const int dp = t & 15;                   // dim pair 0..15
    const char* vp = (const char*)(vT + (size_t)plane * LTOK * 32) + dp * 4;
    float acc0 = 0.f, acc1 = 0.f;
    #pragma unroll
    for (int p = 0; p < 16; ++p) {
        const int sl = tl * 16 + p;
        #pragma unroll
        for (int c = 0; c < 4; ++c) {
            const float w = s_w[sl][c];
            const unsigned int u = *(const unsigned int*)(vp + s_o[sl][c]);
            acc0 = fmaf(w, bflo(u), acc0);
            acc1 = fmaf(w, bfhi(u), acc1);
        }
    }
    const unsigned int o = (unsigned)f2bf(acc0) | ((unsigned)f2bf(acc1) << 16);
    *(unsigned int*)(samp + (size_t)(b * LTOK + s0 + tl) * 256 + h * 32 + dp * 2) = o;
}

// ---------------------------------------------------------------------------
// LayerNorm over D=256: out = LN(a + b) * g + be. One wave per token.
// a, b each f32 or bf16 per flags; outputs f32 and/or bf16.
// ---------------------------------------------------------------------------
__global__ __launch_bounds__(256) void ln_kernel(
    const void* __restrict__ a, int a_bf16,
    const void* __restrict__ b, int b_bf16,
    const float* __restrict__ g, const float* __restrict__ be,
    float* __restrict__ outF, unsigned short* __restrict__ outB)
{
    const int wid  = threadIdx.x >> 6;
    const int lane = threadIdx.x & 63;
    const int tok  = blockIdx.x * 4 + wid;
    const size_t base = (size_t)tok * 256 + lane * 4;

    float4 va, vb;
    if (a_bf16) {
        const ushort4 u = *(const ushort4*)((const unsigned short*)a + base);
        va.x = bf2f(u.x); va.y = bf2f(u.y); va.z = bf2f(u.z); va.w = bf2f(u.w);
    } else {
        va = *(const float4*)((const float*)a + base);
    }
    if (b_bf16) {
        const ushort4 u = *(const ushort4*)((const unsigned short*)b + base);
        vb.x = bf2f(u.x); vb.y = bf2f(u.y); vb.z = bf2f(u.z); vb.w = bf2f(u.w);
    } else {
        vb = *(const float4*)((const float*)b + base);
    }
    float4 v;
    v.x = va.x + vb.x; v.y = va.y + vb.y; v.z = va.z + vb.z; v.w = va.w + vb.w;

    float s  = v.x + v.y + v.z + v.w;
    float sq = v.x * v.x + v.y * v.y + v.z * v.z + v.w * v.w;
    #pragma unroll
    for (int m = 32; m; m >>= 1) {
        s  += __shfl_xor(s, m, 64);
        sq += __shfl_xor(sq, m, 64);
    }
    const float mean = s * (1.f / 256.f);
    const float var  = sq * (1.f / 256.f) - mean * mean;
    const float rs   = rsqrtf(var + 1e-5f);

    const float4 g4 = *(const float4*)(g + lane * 4);
    const float4 b4 = *(const float4*)(be + lane * 4);
    float4 o;
    o.x = (v.x - mean) * rs * g4.x + b4.x;
    o.y = (v.y - mean) * rs * g4.y + b4.y;
    o.z = (v.z - mean) * rs * g4.z + b4.z;
    o.w = (v.w - mean) * rs * g4.w + b4.w;
    if (outF) *(float4*)(outF + base) = o;
    if (outB) {
        ushort4 u;
        u.x = f2bf(o.x); u.y = f2bf(o.y); u.z = f2bf(o.z); u.w = f2bf(o.w);
        *(ushort4*)(outB + base) = u;
    }
}

// ---------------------------------------------------------------------------
extern "C" void kernel_launch(void* const* d_in, const int* in_sizes, int n_in,
                              void* d_out, int out_size, void* d_ws, size_t ws_size,
                              hipStream_t stream)
{
    const float* src   = (const float*)d_in[0];
    const float* pos   = (const float*)d_in[1];
    const float* ref   = (const float*)d_in[2];
    const int*   sshap = (const int*)d_in[3];
    const int*   lstrt = (const int*)d_in[4];
    const unsigned char* mask = (const unsigned char*)d_in[5];
    const float* w_off = (const float*)d_in[6];
    const float* b_off = (const float*)d_in[7];
    const float* w_att = (const float*)d_in[8];
    const float* b_att = (const float*)d_in[9];
    const float* w_val = (const float*)d_in[10];
    const float* b_val = (const float*)d_in[11];
    const float* w_out = (const float*)d_in[12];
    const float* b_out = (const float*)d_in[13];
    const float* ln1g  = (const float*)d_in[14];
    const float* ln1b  = (const float*)d_in[15];
    const float* w1    = (const float*)d_in[16];
    const float* b1    = (const float*)d_in[17];
    const float* w2    = (const float*)d_in[18];
    const float* b2    = (const float*)d_in[19];
    const float* ln2g  = (const float*)d_in[20];
    const float* ln2b  = (const float*)d_in[21];
    float* out = (float*)d_out;

    // ---- workspace layout (~135 MB), time-disjoint reuse ----
    // [0,        1.5 SZB)  qpf f32 [NTOK][384]  -> aof f32 [NTOK][256] at [0,SZB)
    //                                           -> hidden bf16 [NTOK][1024] at [0,2SZB)
    // [1.5 SZB,  2.0 SZB)  vT bf16 head-major   (dead after sample)
    // [2.0 SZB,  2.5 SZB)  samp16 bf16          -> ffb bf16 [NTOK][256]
    // [2.5 SZB,  3.0 SZB)  xb bf16
    // [3.0 SZB,  +1.5 MB)  weights bf16 + bias concat
    const size_t SZB = (size_t)NTOK * 256 * 4;        // 44.56 MB
    char* w = (char*)d_ws;
    float*          qpf    = (float*)w;
    float*          aof    = (float*)w;
    unsigned short* hidb   = (unsigned short*)w;                    // [NTOK][1024]
    unsigned short* vT     = (unsigned short*)(w + SZB * 3 / 2);
    unsigned short* samp16 = (unsigned short*)(w + SZB * 2);
    unsigned short* ffb    = samp16;                  // reuse after samp dead
    unsigned short* xb     = (unsigned short*)(w + SZB * 2 + SZB / 2);
    char* wreg = w + SZB * 3;
    unsigned short* wvalT  = (unsigned short*)wreg;
    unsigned short* woaT   = wvalT + 256 * 256;       // [384][256]
    unsigned short* woutT  = woaT + 384 * 256;
    unsigned short* w1T    = woutT + 256 * 256;
    unsigned short* w2T    = w1T + 1024 * 256;
    float*          bcat   = (float*)(w2T + 256 * 1024);

    const dim3 blk(256);
    const dim3 tblk(32, 8);

    // weights -> bf16 transposed [N][K]
    transpose_cast<<<dim3(8, 8),  tblk, 0, stream>>>(w_val, wvalT, 256, 256);
    transpose_cast<<<dim3(8, 8),  tblk, 0, stream>>>(w_off, woaT,  256, 256);
    transpose_cast<<<dim3(8, 4),  tblk, 0, stream>>>(w_att, woaT + 256 * 256, 256, 128);
    transpose_cast<<<dim3(8, 8),  tblk, 0, stream>>>(w_out, woutT, 256, 256);
    transpose_cast<<<dim3(8, 32), tblk, 0, stream>>>(w1,    w1T,   256, 1024);
    transpose_cast<<<dim3(32, 8), tblk, 0, stream>>>(w2,    w2T,   1024, 256);
    concat_bias<<<1, 384, 0, stream>>>(b_off, b_att, bcat);

    // value = src @ w_val + b_val (masked) -> vT head-major bf16
    gemm_mfma<<<dim3(2, NTOK / TM), blk, 0, stream>>>(
        src, nullptr, wvalT, b_val, nullptr, vT, NTOK, 256, 256, 0, 0, 1, mask);
    // qproj = (src+pos) @ [w_off|w_att] + [b_off|b_att] -> qpf f32 [NTOK][384]
    gemm_mfma<<<dim3(3, NTOK / TM), blk, 0, stream>>>(
        src, pos, woaT, bcat, qpf, nullptr, NTOK, 384, 256, 0, 0, 0, nullptr);

    // softmax + bilinear sampling -> samp16
    sample_kernel<<<dim3(16 * (LTOK / 16)), blk, 0, stream>>>(
        vT, qpf, ref, sshap, lstrt, samp16);

    // attn_out = samp @ w_out + b_out -> aof (qpf dead)
    gemm_mfma<<<dim3(2, NTOK / TM), blk, 0, stream>>>(
        samp16, nullptr, woutT, b_out, aof, nullptr, NTOK, 256, 256, 1, 0, 0, nullptr);

    // x = LN1(src + attn_out) -> xb bf16
    ln_kernel<<<dim3(NTOK / 4), blk, 0, stream>>>(
        src, 0, aof, 0, ln1g, ln1b, nullptr, xb);

    // FFN unchunked: hidden = relu(x @ w1 + b1) bf16 (aof/qpf dead);
    // ffn = hidden @ w2 + b2 -> ffb bf16 (samp dead)
    gemm_mfma<<<dim3(8, NTOK / TM), blk, 0, stream>>>(
        xb, nullptr, w1T, b1, nullptr, hidb, NTOK, DFFN, 256, 1, 1, 0, nullptr);
    gemm_mfma<<<dim3(2, NTOK / TM), blk, 0, stream>>>(
        hidb, nullptr, w2T, b2, nullptr, ffb, NTOK, 256, DFFN, 1, 0, 0, nullptr);

    // out = LN2(x + ffn)
    ln_kernel<<<dim3(NTOK / 4), blk, 0, stream>>>(
        xb, 1, ffb, 1, ln2g, ln2b, out, nullptr);
}

// Round 6
// 522.949 us; speedup vs baseline: 3.1433x; 1.0472x over previous
//
#include <hip/hip_runtime.h>
#include <hip/hip_bf16.h>

// Problem constants
#define BSZ      2
#define LTOK     21760            // 128*128 + 64*64 + 32*32 + 16*16
#define NTOK     (BSZ * LTOK)     // 43520 = 128 * 340
#define DMODEL   256
#define DFFN     1024

typedef __attribute__((ext_vector_type(8))) short short8;   // 8 bf16 = 4 VGPRs
typedef __attribute__((ext_vector_type(4))) float f32x4;

__device__ __forceinline__ unsigned short f2bf(float x) {
    __hip_bfloat16 h = __float2bfloat16(x);
    return *reinterpret_cast<unsigned short*>(&h);
}
__device__ __forceinline__ float bf2f(unsigned short u) {
    union { unsigned int i; float f; } c; c.i = ((unsigned int)u) << 16; return c.f;
}
__device__ __forceinline__ float bflo(unsigned int u) {
    union { unsigned int i; float f; } c; c.i = u << 16; return c.f;
}
__device__ __forceinline__ float bfhi(unsigned int u) {
    union { unsigned int i; float f; } c; c.i = u & 0xffff0000u; return c.f;
}

// ---------------------------------------------------------------------------
// bf16 MFMA GEMM:  C[M x N] = A @ Bt^T (+bias) with Bt = [N][K] bf16.
// 128x128 tile, BK=32, 4 waves 2x2, each wave 4x4 tiles of 16x16x32.
// LDS in MFMA fragment order (64 x 16 B slots per 16x32 sub-tile).
// amode 0: A f32 [M][K] (+optional A2), cast in staging.  amode 1: A bf16.
// Output (Cb bf16) goes through an LDS-staged vectorized epilogue:
//   4 slabs of 32 rows x 128 cols, written as 512 uint4 (16 B) stores each —
//   full-line writes (fixes the 2.2x WRITE amplification of scalar ushort
//   stores seen in rocprof round 5).
// cmode 0: row-major.  cmode 1: head-major vT[((b*8+h)*LTOK+s)*32+d].
// ---------------------------------------------------------------------------
#define TM 128
#define TN 128
#define TBK 32
#define EBS 132   // epilogue LDS row stride (ushorts): spreads r0 groups over banks

__global__ __launch_bounds__(256) void gemm_mfma(
    const void* __restrict__ Av, const float* __restrict__ A2,
    const unsigned short* __restrict__ Bt, const float* __restrict__ bias,
    unsigned short* __restrict__ Cb,
    int M, int N, int K, int amode, int relu, int cmode,
    const unsigned char* __restrict__ mask)
{
    // single 16 KB block so the epilogue can reuse it contiguously
    __shared__ __align__(16) unsigned short smem[TM * TBK + TN * TBK];
    unsigned short* sA = smem;
    unsigned short* sB = smem + TM * TBK;

    const int tid  = threadIdx.x;
    const int lane = tid & 63;
    const int wave = tid >> 6;
    const int wm = wave >> 1, wn = wave & 1;

    const int bm = blockIdx.y * TM;
    const int bn = blockIdx.x * TN;

    const int sr = tid >> 6;           // staging sub-tile base (0..3)
    const int fr = lane & 15;          // row within sub-tile
    const int fk = (lane >> 4) * 8;    // k offset (0,8,16,24)

    f32x4 acc[4][4];
    #pragma unroll
    for (int i = 0; i < 4; ++i)
        #pragma unroll
        for (int j = 0; j < 4; ++j)
            acc[i][j] = (f32x4){0.f, 0.f, 0.f, 0.f};

    for (int k0 = 0; k0 < K; k0 += TBK) {
        #pragma unroll
        for (int rr = 0; rr < 2; ++rr) {
            const int s = sr + rr * 4;
            const size_t grow = (size_t)(bm + s * 16 + fr);
            unsigned short* dst = &sA[s * 512 + lane * 8];
            if (amode == 0) {
                const float* Af = (const float*)Av + grow * K + k0 + fk;
                float4 v0 = *(const float4*)Af;
                float4 v1 = *(const float4*)(Af + 4);
                if (A2) {
                    const float* Pf = A2 + grow * K + k0 + fk;
                    const float4 p0 = *(const float4*)Pf;
                    const float4 p1 = *(const float4*)(Pf + 4);
                    v0.x += p0.x; v0.y += p0.y; v0.z += p0.z; v0.w += p0.w;
                    v1.x += p1.x; v1.y += p1.y; v1.z += p1.z; v1.w += p1.w;
                }
                const unsigned int p0 = (unsigned)f2bf(v0.x) | ((unsigned)f2bf(v0.y) << 16);
                const unsigned int p1 = (unsigned)f2bf(v0.z) | ((unsigned)f2bf(v0.w) << 16);
                const unsigned int p2 = (unsigned)f2bf(v1.x) | ((unsigned)f2bf(v1.y) << 16);
                const unsigned int p3 = (unsigned)f2bf(v1.z) | ((unsigned)f2bf(v1.w) << 16);
                *(uint4*)dst = make_uint4(p0, p1, p2, p3);
            } else {
                const unsigned short* Ab = (const unsigned short*)Av + grow * K + k0 + fk;
                *(uint4*)dst = *(const uint4*)Ab;
            }
        }
        #pragma unroll
        for (int rr = 0; rr < 2; ++rr) {
            const int s = sr + rr * 4;
            const size_t gn = (size_t)(bn + s * 16 + fr);
            *(uint4*)&sB[s * 512 + lane * 8] = *(const uint4*)(Bt + gn * K + k0 + fk);
        }
        __syncthreads();

        short8 af[4], bfr[4];
        #pragma unroll
        for (int i = 0; i < 4; ++i)
            af[i] = *(const short8*)&sA[(wm * 4 + i) * 512 + lane * 8];
        #pragma unroll
        for (int j = 0; j < 4; ++j)
            bfr[j] = *(const short8*)&sB[(wn * 4 + j) * 512 + lane * 8];
        #pragma unroll
        for (int i = 0; i < 4; ++i)
            #pragma unroll
            for (int j = 0; j < 4; ++j)
                acc[i][j] = __builtin_amdgcn_mfma_f32_16x16x32_bf16(
                    af[i], bfr[j], acc[i][j], 0, 0, 0);
        __syncthreads();
    }

    // ---- vectorized epilogue ----
    // MFMA C/D layout: col = lane&15, row = (lane>>4)*4 + reg.
    const int r0 = (lane >> 4) * 4;
    const int c0 = lane & 15;
    unsigned short* eb = smem;   // 32 x EBS ushorts = 8448 B, fits in 16 KB

    #pragma unroll
    for (int i = 0; i < 4; ++i) {
        if (i) __syncthreads();          // previous slab's reads done
        #pragma unroll
        for (int j = 0; j < 4; ++j) {
            const int col = bn + wn * 64 + j * 16 + c0;
            const float bj = bias ? bias[col] : 0.f;
            #pragma unroll
            for (int r = 0; r < 4; ++r) {
                const int row = bm + wm * 64 + i * 16 + r0 + r;
                float v = acc[i][j][r] + bj;
                if (relu) v = fmaxf(v, 0.f);
                if (mask && mask[row]) v = 0.f;
                eb[(wm * 16 + r0 + r) * EBS + wn * 64 + j * 16 + c0] = f2bf(v);
            }
        }
        __syncthreads();                 // slab staged
        #pragma unroll
        for (int qq = 0; qq < 2; ++qq) {
            const int q  = tid + qq * 256;        // 512 chunks = 32 rows x 16
            const int rl = q >> 4;                // local row 0..31 (wm-major)
            const int ch = q & 15;                // 16 B chunk within 128 cols
            const int grow = bm + (rl >> 4) * 64 + i * 16 + (rl & 15);
            const uint4 val = *(const uint4*)&eb[rl * EBS + ch * 8];
            if (cmode == 1) {
                const int bb   = grow >= LTOK;
                const int srow = grow - bb * LTOK;
                const int hcol = (bn + ch * 8) >> 5;     // head (N==256)
                const int d    = (ch & 3) * 8;
                *(uint4*)&Cb[((size_t)(bb * 8 + hcol) * LTOK + srow) * 32 + d] = val;
            } else {
                *(uint4*)&Cb[(size_t)grow * N + bn + ch * 8] = val;
            }
        }
    }
}

// ---------------------------------------------------------------------------
// Weight transpose + cast: W[K][N] f32 -> Wt[N][K] bf16 (K,N mult of 32)
// ---------------------------------------------------------------------------
__global__ void transpose_cast(const float* __restrict__ W,
                               unsigned short* __restrict__ Wt, int K, int N)
{
    __shared__ float t[32][33];
    const int k0 = blockIdx.x * 32, n0 = blockIdx.y * 32;
    const int tx = threadIdx.x, ty = threadIdx.y;   // 32 x 8
    #pragma unroll
    for (int i = 0; i < 32; i += 8)
        t[ty + i][tx] = W[(size_t)(k0 + ty + i) * N + n0 + tx];
    __syncthreads();
    #pragma unroll
    for (int i = 0; i < 32; i += 8)
        Wt[(size_t)(n0 + ty + i) * K + k0 + tx] = f2bf(t[tx][ty + i]);
}

__global__ void concat_bias(const float* __restrict__ b_off,
                            const float* __restrict__ b_att,
                            float* __restrict__ dst)
{
    const int t = threadIdx.x;   // 384 threads
    dst[t] = (t < 256) ? b_off[t] : b_att[t - 256];
}

// ---------------------------------------------------------------------------
// Fused softmax + bilinear sampling, head-major value, qp in bf16.
// Block = (plane, 16-token chunk); plane = blockIdx % 16 pins a plane to one
// XCD (2 planes = 2.7 MB < 4 MB L2). Grid = 16 * (LTOK/16).
// ---------------------------------------------------------------------------
__global__ __launch_bounds__(256) void sample_kernel(
    const unsigned short* __restrict__ vT, const unsigned short* __restrict__ qp,
    const float* __restrict__ ref,
    const int* __restrict__ sshapes, const int* __restrict__ lstart,
    unsigned short* __restrict__ samp)
{
    __shared__ float s_w[256][4];
    __shared__ int   s_o[256][4];   // byte offsets into the plane

    const int blk   = blockIdx.x;
    const int plane = blk & 15;
    const int chunk = blk >> 4;              // 0 .. LTOK/16-1
    const int b = plane >> 3;
    const int h = plane & 7;
    const int s0 = chunk * 16;               // token offset within plane
    const int t = threadIdx.x;

    // ---- phase A: per (token, point) ----
    {
        const int tl = t >> 4;               // 0..15 token in chunk
        const int p  = t & 15;
        const int l  = p >> 2;
        const int pp = p & 3;
        const int H = sshapes[2 * l], W = sshapes[2 * l + 1];
        const float Wf = (float)W, Hf = (float)H;
        const size_t tok = (size_t)(b * LTOK + s0 + tl);

        const float ox = bf2f(qp[tok * 384 + h * 32 + l * 8 + pp * 2 + 0]);
        const float oy = bf2f(qp[tok * 384 + h * 32 + l * 8 + pp * 2 + 1]);
        const float rx = ref[tok * 8 + l * 2 + 0];
        const float ry = ref[tok * 8 + l * 2 + 1];

        const float x = (rx + ox / Wf) * Wf - 0.5f;
        const float y = (ry + oy / Hf) * Hf - 0.5f;
        const float x0 = floorf(x), y0 = floorf(y);
        const float dx = x - x0, dy = y - y0;
        const int x0i = (int)x0, y0i = (int)y0;
        const int s = lstart[l];

        // softmax prob over the 16 points of this head (16-lane groups)
        const float a = bf2f(qp[tok * 384 + 256 + h * 16 + p]);
        float mx = a;
        #pragma unroll
        for (int m = 8; m; m >>= 1) mx = fmaxf(mx, __shfl_xor(mx, m, 16));
        const float e = __expf(a - mx);
        float ssum = e;
        #pragma unroll
        for (int m = 8; m; m >>= 1) ssum += __shfl_xor(ssum, m, 16);
        const float prob = e / ssum;

        const float cw[4] = {(1.f - dx) * (1.f - dy), dx * (1.f - dy),
                             (1.f - dx) * dy,         dx * dy};
        const int cx[4] = {x0i, x0i + 1, x0i,     x0i + 1};
        const int cy[4] = {y0i, y0i,     y0i + 1, y0i + 1};
        #pragma unroll
        for (int c = 0; c < 4; ++c) {
            const bool valid = (cx[c] >= 0) & (cx[c] < W) & (cy[c] >= 0) & (cy[c] < H);
            const int xi = min(max(cx[c], 0), W - 1);
            const int yi = min(max(cy[c], 0), H - 1);
            s_o[t][c] = (s + yi * W + xi) * 64;          // byte offset (32 bf16)
            s_w[t][c] = valid ? cw[c] * prob : 0.f;
        }
    }
    __syncthreads();

    // ---- phase B: gather-accumulate, (token, dim-pair) ----
    const int tl = t >> 4;                   // 0..15
    const int dp = t & 15;                   // dim pair 0..15
    const char* vp = (const char*)(vT + (size_t)plane * LTOK * 32) + dp * 4;
    float acc0 = 0.f, acc1 = 0.f;
    #pragma unroll
    for (int p = 0; p < 16; ++p) {
        const int sl = tl * 16 + p;
        #pragma unroll
        for (int c = 0; c < 4; ++c) {
            const float w = s_w[sl][c];
            const unsigned int u = *(const unsigned int*)(vp + s_o[sl][c]);
            acc0 = fmaf(w, bflo(u), acc0);
            acc1 = fmaf(w, bfhi(u), acc1);
        }
    }
    const unsigned int o = (unsigned)f2bf(acc0) | ((unsigned)f2bf(acc1) << 16);
    *(unsigned int*)(samp + (size_t)(b * LTOK + s0 + tl) * 256 + h * 32 + dp * 2) = o;
}

// ---------------------------------------------------------------------------
// LayerNorm over D=256: out = LN(a + b) * g + be. One wave per token.
// a, b each f32 or bf16 per flags; outputs f32 and/or bf16.
// ---------------------------------------------------------------------------
__global__ __launch_bounds__(256) void ln_kernel(
    const void* __restrict__ a, int a_bf16,
    const void* __restrict__ b, int b_bf16,
    const float* __restrict__ g, const float* __restrict__ be,
    float* __restrict__ outF, unsigned short* __restrict__ outB)
{
    const int wid  = threadIdx.x >> 6;
    const int lane = threadIdx.x & 63;
    const int tok  = blockIdx.x * 4 + wid;
    const size_t base = (size_t)tok * 256 + lane * 4;

    float4 va, vb;
    if (a_bf16) {
        const ushort4 u = *(const ushort4*)((const unsigned short*)a + base);
        va.x = bf2f(u.x); va.y = bf2f(u.y); va.z = bf2f(u.z); va.w = bf2f(u.w);
    } else {
        va = *(const float4*)((const float*)a + base);
    }
    if (b_bf16) {
        const ushort4 u = *(const ushort4*)((const unsigned short*)b + base);
        vb.x = bf2f(u.x); vb.y = bf2f(u.y); vb.z = bf2f(u.z); vb.w = bf2f(u.w);
    } else {
        vb = *(const float4*)((const float*)b + base);
    }
    float4 v;
    v.x = va.x + vb.x; v.y = va.y + vb.y; v.z = va.z + vb.z; v.w = va.w + vb.w;

    float s  = v.x + v.y + v.z + v.w;
    float sq = v.x * v.x + v.y * v.y + v.z * v.z + v.w * v.w;
    #pragma unroll
    for (int m = 32; m; m >>= 1) {
        s  += __shfl_xor(s, m, 64);
        sq += __shfl_xor(sq, m, 64);
    }
    const float mean = s * (1.f / 256.f);
    const float var  = sq * (1.f / 256.f) - mean * mean;
    const float rs   = rsqrtf(var + 1e-5f);

    const float4 g4 = *(const float4*)(g + lane * 4);
    const float4 b4 = *(const float4*)(be + lane * 4);
    float4 o;
    o.x = (v.x - mean) * rs * g4.x + b4.x;
    o.y = (v.y - mean) * rs * g4.y + b4.y;
    o.z = (v.z - mean) * rs * g4.z + b4.z;
    o.w = (v.w - mean) * rs * g4.w + b4.w;
    if (outF) *(float4*)(outF + base) = o;
    if (outB) {
        ushort4 u;
        u.x = f2bf(o.x); u.y = f2bf(o.y); u.z = f2bf(o.z); u.w = f2bf(o.w);
        *(ushort4*)(outB + base) = u;
    }
}

// ---------------------------------------------------------------------------
extern "C" void kernel_launch(void* const* d_in, const int* in_sizes, int n_in,
                              void* d_out, int out_size, void* d_ws, size_t ws_size,
                              hipStream_t stream)
{
    const float* src   = (const float*)d_in[0];
    const float* pos   = (const float*)d_in[1];
    const float* ref   = (const float*)d_in[2];
    const int*   sshap = (const int*)d_in[3];
    const int*   lstrt = (const int*)d_in[4];
    const unsigned char* mask = (const unsigned char*)d_in[5];
    const float* w_off = (const float*)d_in[6];
    const float* b_off = (const float*)d_in[7];
    const float* w_att = (const float*)d_in[8];
    const float* b_att = (const float*)d_in[9];
    const float* w_val = (const float*)d_in[10];
    const float* b_val = (const float*)d_in[11];
    const float* w_out = (const float*)d_in[12];
    const float* b_out = (const float*)d_in[13];
    const float* ln1g  = (const float*)d_in[14];
    const float* ln1b  = (const float*)d_in[15];
    const float* w1    = (const float*)d_in[16];
    const float* b1    = (const float*)d_in[17];
    const float* w2    = (const float*)d_in[18];
    const float* b2    = (const float*)d_in[19];
    const float* ln2g  = (const float*)d_in[20];
    const float* ln2b  = (const float*)d_in[21];
    float* out = (float*)d_out;

    // ---- workspace layout (~135 MB), time-disjoint reuse ----
    // [0,        1.5 SZB)  qpb bf16 [NTOK][384] -> aof16 bf16 [NTOK][256]
    //                                           -> hidb bf16 [NTOK][1024] ([0,2SZB))
    // [1.5 SZB,  2.0 SZB)  vT bf16 head-major   (dead after sample)
    // [2.0 SZB,  2.5 SZB)  samp16 bf16          -> ffb bf16 [NTOK][256]
    // [2.5 SZB,  3.0 SZB)  xb bf16
    // [3.0 SZB,  +1.5 MB)  weights bf16 + bias concat
    const size_t SZB = (size_t)NTOK * 256 * 4;        // 44.56 MB
    char* w = (char*)d_ws;
    unsigned short* qpb    = (unsigned short*)w;                    // [NTOK][384]
    unsigned short* aof16  = (unsigned short*)w;                    // [NTOK][256]
    unsigned short* hidb   = (unsigned short*)w;                    // [NTOK][1024]
    unsigned short* vT     = (unsigned short*)(w + SZB * 3 / 2);
    unsigned short* samp16 = (unsigned short*)(w + SZB * 2);
    unsigned short* ffb    = samp16;                  // reuse after samp dead
    unsigned short* xb     = (unsigned short*)(w + SZB * 2 + SZB / 2);
    char* wreg = w + SZB * 3;
    unsigned short* wvalT  = (unsigned short*)wreg;
    unsigned short* woaT   = wvalT + 256 * 256;       // [384][256]
    unsigned short* woutT  = woaT + 384 * 256;
    unsigned short* w1T    = woutT + 256 * 256;
    unsigned short* w2T    = w1T + 1024 * 256;
    float*          bcat   = (float*)(w2T + 256 * 1024);

    const dim3 blk(256);
    const dim3 tblk(32, 8);

    // weights -> bf16 transposed [N][K]
    transpose_cast<<<dim3(8, 8),  tblk, 0, stream>>>(w_val, wvalT, 256, 256);
    transpose_cast<<<dim3(8, 8),  tblk, 0, stream>>>(w_off, woaT,  256, 256);
    transpose_cast<<<dim3(8, 4),  tblk, 0, stream>>>(w_att, woaT + 256 * 256, 256, 128);
    transpose_cast<<<dim3(8, 8),  tblk, 0, stream>>>(w_out, woutT, 256, 256);
    transpose_cast<<<dim3(8, 32), tblk, 0, stream>>>(w1,    w1T,   256, 1024);
    transpose_cast<<<dim3(32, 8), tblk, 0, stream>>>(w2,    w2T,   1024, 256);
    concat_bias<<<1, 384, 0, stream>>>(b_off, b_att, bcat);

    // value = src @ w_val + b_val (masked) -> vT head-major bf16
    gemm_mfma<<<dim3(2, NTOK / TM), blk, 0, stream>>>(
        src, nullptr, wvalT, b_val, vT, NTOK, 256, 256, 0, 0, 1, mask);
    // qproj = (src+pos) @ [w_off|w_att] + bcat -> qpb bf16 [NTOK][384]
    gemm_mfma<<<dim3(3, NTOK / TM), blk, 0, stream>>>(
        src, pos, woaT, bcat, qpb, NTOK, 384, 256, 0, 0, 0, nullptr);

    // softmax + bilinear sampling -> samp16
    sample_kernel<<<dim3(16 * (LTOK / 16)), blk, 0, stream>>>(
        vT, qpb, ref, sshap, lstrt, samp16);

    // attn_out = samp @ w_out + b_out -> aof16 (qpb dead)
    gemm_mfma<<<dim3(2, NTOK / TM), blk, 0, stream>>>(
        samp16, nullptr, woutT, b_out, aof16, NTOK, 256, 256, 1, 0, 0, nullptr);

    // x = LN1(src + attn_out) -> xb bf16
    ln_kernel<<<dim3(NTOK / 4), blk, 0, stream>>>(
        src, 0, aof16, 1, ln1g, ln1b, nullptr, xb);

    // FFN unchunked: hidden = relu(x @ w1 + b1) bf16 (aof/qpb dead);
    // ffn = hidden @ w2 + b2 -> ffb bf16 (samp dead)
    gemm_mfma<<<dim3(8, NTOK / TM), blk, 0, stream>>>(
        xb, nullptr, w1T, b1, hidb, NTOK, DFFN, 256, 1, 1, 0, nullptr);
    gemm_mfma<<<dim3(2, NTOK / TM), blk, 0, stream>>>(
        hidb, nullptr, w2T, b2, ffb, NTOK, 256, DFFN, 1, 0, 0, nullptr);

    // out = LN2(x + ffn)
    ln_kernel<<<dim3(NTOK / 4), blk, 0, stream>>>(
        xb, 1, ffb, 1, ln2g, ln2b, out, nullptr);
}